// Round 15
// baseline (281.975 us; speedup 1.0000x reference)
//
#include <hip/hip_runtime.h>
#include <hip/hip_fp16.h>
#include <cstdint>
#include <cstddef>

#define N_NODES 50000
#define N_EDGES 1600000
#define NEG_SLOPE 0.2f
#define GAT_EPS 1e-16f

#define NCHUNK 128
#define CE (N_EDGES / NCHUNK)   // 12500
#define NBKT 196                 // ceil(50000/256)
#define GEMM_BLOCKS 782          // ceil(50000/64)

typedef _Float16 half8v __attribute__((ext_vector_type(8)));
typedef _Float16 half4v __attribute__((ext_vector_type(4)));
typedef float f32x4 __attribute__((ext_vector_type(4)));
typedef int i32x4 __attribute__((ext_vector_type(4)));

// Channel permutation for h1 storage (MFMA C-reg native order):
// real c = ct*16 + m  <->  cperm = m*8 + ct

// ---------------- fused: MFMA GEMM blocks + histogram blocks + W2-prep block ----------------

__global__ __launch_bounds__(256) void k_gh(
    const float* __restrict__ x, const float* __restrict__ W1,
    const float* __restrict__ W2, const float* __restrict__ b1,
    const float* __restrict__ att_src, const float* __restrict__ att_dst,
    _Float16* __restrict__ h1p, float* __restrict__ a_src, float* __restrict__ a_dst,
    const int* __restrict__ ei, int* __restrict__ coarse,
    float* __restrict__ w2tp, float* __restrict__ b1p) {
    __shared__ __align__(16) char smem[34816];
    int t = threadIdx.x;
    int b = blockIdx.x;
    if (b == GEMM_BLOCKS + NCHUNK) {
        // ---- W2^T / b1 permuted prep (consumed by k_agg1f, a later kernel) ----
        for (int i = t; i < 2112; i += 256) {   // 16 x 132
            int j = i / 132, kp = i % 132;
            float v = 0.f;
            if (kp < 128) {
                int real = (kp & 7) * 16 + (kp >> 3);
                v = W2[real * 16 + j];
            }
            w2tp[i] = v;
        }
        if (t < 128) {
            int real = (t & 7) * 16 + (t >> 3);
            b1p[t] = b1[real];
        }
        return;
    }
    if (b >= GEMM_BLOCKS) {
        // ---- histogram branch ----
        int* h = (int*)smem;
        int g = b - GEMM_BLOCKS;
        if (t < NBKT) h[t] = 0;
        __syncthreads();
        int e0 = g * CE;
        for (int e = e0 + t; e < e0 + CE; e += 256)
            atomicAdd(&h[ei[N_EDGES + e] >> 8], 1);
        __syncthreads();
        if (t < NBKT) coarse[t * NCHUNK + g] = h[t];
        return;
    }
    // ---- MFMA GEMM branch: stage W1^T fp16 straight from W1 ----
    _Float16* wl = (_Float16*)smem;      // [128][136]
    for (int j = t; j < 16384; j += 256) {
        int k = j >> 7, c = j & 127;
        wl[c * 136 + k] = (_Float16)W1[j];
    }
    __syncthreads();
    int wv = t >> 6, lane = t & 63;
    int m = lane & 15, q = lane >> 4;
    int nb = b * 64 + wv * 16;
    int grow = nb + m;
    const float* xrow = x + (size_t)((grow < N_NODES) ? grow : (N_NODES - 1)) * 128;
    f32x4 acc[8];
#pragma unroll
    for (int ct = 0; ct < 8; ++ct) acc[ct] = (f32x4){0.f, 0.f, 0.f, 0.f};
#pragma unroll
    for (int kc = 0; kc < 4; ++kc) {
        float4 u0 = *(const float4*)(xrow + kc * 32 + q * 8);
        float4 u1 = *(const float4*)(xrow + kc * 32 + q * 8 + 4);
        half8v a;
        a[0] = (_Float16)u0.x; a[1] = (_Float16)u0.y;
        a[2] = (_Float16)u0.z; a[3] = (_Float16)u0.w;
        a[4] = (_Float16)u1.x; a[5] = (_Float16)u1.y;
        a[6] = (_Float16)u1.z; a[7] = (_Float16)u1.w;
#pragma unroll
        for (int ct = 0; ct < 8; ++ct) {
            half8v bf = *(const half8v*)(wl + (ct * 16 + m) * 136 + kc * 32 + q * 8);
            acc[ct] = __builtin_amdgcn_mfma_f32_16x16x32_f16(a, bf, acc[ct], 0, 0, 0);
        }
    }
    float att_s[8], att_d[8];
#pragma unroll
    for (int ct = 0; ct < 8; ++ct) {
        att_s[ct] = att_src[ct * 16 + m];
        att_d[ct] = att_dst[ct * 16 + m];
    }
#pragma unroll
    for (int r = 0; r < 4; ++r) {
        int gn = nb + q * 4 + r;
        half8v hv;
        float ps0 = 0.f, ps1 = 0.f, pd0 = 0.f, pd1 = 0.f;
#pragma unroll
        for (int ct = 0; ct < 8; ++ct) {
            float v = acc[ct][r];
            hv[ct] = (_Float16)v;
            if (ct < 4) { ps0 += v * att_s[ct]; pd0 += v * att_d[ct]; }
            else        { ps1 += v * att_s[ct]; pd1 += v * att_d[ct]; }
        }
#pragma unroll
        for (int off = 8; off >= 1; off >>= 1) {
            ps0 += __shfl_xor(ps0, off, 64);
            ps1 += __shfl_xor(ps1, off, 64);
            pd0 += __shfl_xor(pd0, off, 64);
            pd1 += __shfl_xor(pd1, off, 64);
        }
        if (gn < N_NODES) {
            *(half8v*)(h1p + (size_t)gn * 128 + m * 8) = hv;
            if (m == 0) {
                a_src[gn * 2 + 0] = ps0;
                a_src[gn * 2 + 1] = ps1;
                a_dst[gn * 2 + 0] = pd0;
                a_dst[gn * 2 + 1] = pd1;
            }
        }
    }
}

// ---------------- CSR build (LDS atomics only) ----------------

__global__ __launch_bounds__(1024) void k_cscan(const int* __restrict__ coarse,
                                                int* __restrict__ cbase,
                                                int* __restrict__ bb,
                                                int* __restrict__ row_start) {
    __shared__ int cl[NBKT * NCHUNK];   // 100 KB
    __shared__ int btot[NBKT];
    __shared__ int bbase[NBKT];
    int t = threadIdx.x;
    for (int i = t; i < NBKT * NCHUNK; i += 1024) cl[i] = coarse[i];
    __syncthreads();
    if (t < NBKT) {
        int s = 0;
        for (int g = 0; g < NCHUNK; ++g) s += cl[t * NCHUNK + g];
        btot[t] = s;
    }
    __syncthreads();
    if (t == 0) {
        int base = 0;
        for (int b = 0; b < NBKT; ++b) { bbase[b] = base; base += btot[b]; }
    }
    __syncthreads();
    if (t < NBKT) {
        int run = bbase[t];
        bb[t] = run;
        for (int g = 0; g < NCHUNK; ++g) {
            cbase[t * NCHUNK + g] = run;
            run += cl[t * NCHUNK + g];
        }
    }
    if (t == 0) { bb[NBKT] = N_EDGES; row_start[N_NODES] = N_EDGES; }
}

__global__ __launch_bounds__(256) void k_partition(const int* __restrict__ ei,
                                                   const int* __restrict__ cbase,
                                                   int2* __restrict__ part) {
    __shared__ int loc[NBKT];
    int t = threadIdx.x, g = blockIdx.x;
    if (t < NBKT) loc[t] = cbase[t * NCHUNK + g];
    __syncthreads();
    int e0 = g * CE;
    for (int e = e0 + t; e < e0 + CE; e += 256) {
        int s = ei[e], d = ei[N_EDGES + e];
        int slot = atomicAdd(&loc[d >> 8], 1);
        part[slot] = make_int2(s, d);
    }
}

__global__ __launch_bounds__(256) void k_local(const int2* __restrict__ part,
                                               const int* __restrict__ bb,
                                               const float* __restrict__ a_src1,
                                               const float* __restrict__ a_dst1,
                                               int* __restrict__ row_start,
                                               int4* __restrict__ csr) {
    __shared__ int hist[256];
    __shared__ int fillv[256];
    __shared__ float2 adl[256];
    __shared__ int wtot[4];
    int t = threadIdx.x, b = blockIdx.x;
    int n0 = b << 8;
    int es = bb[b], ee = bb[b + 1];
    hist[t] = 0;
    if (n0 + t < N_NODES) adl[t] = ((const float2*)a_dst1)[n0 + t];
    __syncthreads();
    for (int e = es + t; e < ee; e += 256) atomicAdd(&hist[part[e].y - n0], 1);
    __syncthreads();
    int lane = t & 63, w = t >> 6;
    int v = hist[t], x = v;
#pragma unroll
    for (int off = 1; off < 64; off <<= 1) {
        int y = __shfl_up(x, off, 64);
        if (lane >= off) x += y;
    }
    if (lane == 63) wtot[w] = x;
    __syncthreads();
    int woff = 0;
    for (int i = 0; i < w; ++i) woff += wtot[i];
    int excl = woff + x - v;
    if (n0 + t < N_NODES) row_start[n0 + t] = es + excl;
    fillv[t] = excl;
    __syncthreads();
    for (int e = es + t; e < ee; e += 256) {
        int2 sd = part[e];
        int j = sd.y - n0;
        int slot = es + atomicAdd(&fillv[j], 1);
        float2 as = ((const float2*)a_src1)[sd.x];
        float2 ad = adl[j];
        float e0 = as.x + ad.x; e0 = (e0 >= 0.f) ? e0 : NEG_SLOPE * e0;
        float e1 = as.y + ad.y; e1 = (e1 >= 0.f) ? e1 : NEG_SLOPE * e1;
        csr[slot] = make_int4(sd.x, __float_as_int(expf(e0)), __float_as_int(expf(e1)), 0);
    }
}

// ---------------- Layer 1 aggregation + ELU + fused layer-2 GEMM ----------------
// One wave per node, pair-scheme halves; channels in PERMUTED space.
// fp16 gather via mixed-precision FMA; 16 edges/iter => 8 gathers in flight/lane.

__global__ __launch_bounds__(256) void k_agg1f(
    const int* __restrict__ row_start, const int4* __restrict__ csr,
    const _Float16* __restrict__ h1p, const float* __restrict__ b1p,
    const float* __restrict__ w2tp,
    const float* __restrict__ att_src2, const float* __restrict__ att_dst2,
    float* __restrict__ h2, float* __restrict__ as2, float* __restrict__ ad2) {
    __shared__ float w2l[16 * 132];
    __shared__ float rows[4][128];
    int t = threadIdx.x;
    for (int i = t; i < 528; i += 256) ((float4*)w2l)[i] = ((const float4*)w2tp)[i];
    __syncthreads();
    int wv = t >> 6, lane = t & 63;
    int d = blockIdx.x * 4 + wv;
    int row = row_start[d], end = row_start[d + 1];
    int half = lane >> 5;
    int L = lane & 31;
    int c0 = L * 4;
    int head = L & 1;
    float den = 0.f;
    float4 acc = make_float4(0.f, 0.f, 0.f, 0.f);
    int i = row;
    for (; i + 16 <= end; i += 16) {
        int4 e4[8];
        half4v hv[8];
#pragma unroll
        for (int p = 0; p < 8; ++p) e4[p] = csr[i + 2 * p + half];
#pragma unroll
        for (int p = 0; p < 8; ++p)
            hv[p] = *(const half4v*)(h1p + (size_t)e4[p].x * 128 + c0);
#pragma unroll
        for (int p = 0; p < 8; ++p) {
            float we = head ? __int_as_float(e4[p].z) : __int_as_float(e4[p].y);
            den += we;
            acc.x += we * (float)hv[p][0];
            acc.y += we * (float)hv[p][1];
            acc.z += we * (float)hv[p][2];
            acc.w += we * (float)hv[p][3];
        }
    }
    for (; i + 2 <= end; i += 2) {
        int idx = i + half;
        int4 e4 = csr[idx];
        float we = head ? __int_as_float(e4.z) : __int_as_float(e4.y);
        half4v hv = *(const half4v*)(h1p + (size_t)e4.x * 128 + c0);
        den += we;
        acc.x += we * (float)hv[0];
        acc.y += we * (float)hv[1];
        acc.z += we * (float)hv[2];
        acc.w += we * (float)hv[3];
    }
    if (i < end && half == 0) {
        int4 e4 = csr[i];
        float we = head ? __int_as_float(e4.z) : __int_as_float(e4.y);
        half4v hv = *(const half4v*)(h1p + (size_t)e4.x * 128 + c0);
        den += we;
        acc.x += we * (float)hv[0];
        acc.y += we * (float)hv[1];
        acc.z += we * (float)hv[2];
        acc.w += we * (float)hv[3];
    }
    den += __shfl_xor(den, 32, 64);
    acc.x += __shfl_xor(acc.x, 32, 64);
    acc.y += __shfl_xor(acc.y, 32, 64);
    acc.z += __shfl_xor(acc.z, 32, 64);
    acc.w += __shfl_xor(acc.w, 32, 64);
    float inv = 1.f / (den + GAT_EPS);
    float4 bv = ((const float4*)b1p)[L];
    float o0 = acc.x * inv + bv.x;
    float o1 = acc.y * inv + bv.y;
    float o2 = acc.z * inv + bv.z;
    float o3 = acc.w * inv + bv.w;
    o0 = (o0 > 0.f) ? o0 : expm1f(o0);
    o1 = (o1 > 0.f) ? o1 : expm1f(o1);
    o2 = (o2 > 0.f) ? o2 : expm1f(o2);
    o3 = (o3 > 0.f) ? o3 : expm1f(o3);
    if (half == 0) *(float4*)(&rows[wv][c0]) = make_float4(o0, o1, o2, o3);
    // fused gemm2, q-rotated phases
    int j = lane & 15, q = lane >> 4;
    const float* r = rows[wv];
    const float* wt = &w2l[j * 132];
    int k0 = q * 32;
    float acc2 = 0.f;
#pragma unroll
    for (int sI = 0; sI < 8; ++sI) {
        int sp = ((sI + q) & 7) * 4;
        float4 rv = *(const float4*)(r + k0 + sp);
        float4 w4 = *(const float4*)(wt + k0 + sp);
        acc2 += rv.x * w4.x + rv.y * w4.y + rv.z * w4.z + rv.w * w4.w;
    }
    acc2 += __shfl_xor(acc2, 16, 64);
    acc2 += __shfl_xor(acc2, 32, 64);
    if (lane < 16) {
        h2[(size_t)d * 16 + j] = acc2;
        float ps = acc2 * att_src2[j];
        float pd = acc2 * att_dst2[j];
#pragma unroll
        for (int off = 8; off >= 1; off >>= 1) {
            ps += __shfl_xor(ps, off, 64);
            pd += __shfl_xor(pd, off, 64);
        }
        if (lane == 0) { as2[d] = ps; ad2[d] = pd; }
    }
}

// ---------------- Layer 2 aggregation + bias + softmax: one wave per node ----------------

__global__ __launch_bounds__(256) void k_agg2(
    const int* __restrict__ row_start, const int4* __restrict__ csr,
    const float* __restrict__ h2, const float* __restrict__ as2,
    const float* __restrict__ ad2, const float* __restrict__ b2,
    float* __restrict__ out) {
    int t = threadIdx.x;
    int wv = t >> 6, lane = t & 63;
    int d = blockIdx.x * 4 + wv;
    int row = row_start[d], end = row_start[d + 1];
    float ad = ad2[d];
    int c = lane & 15, q = lane >> 4;
    float den = 0.f, acc = 0.f;
    for (int base = row; base < end; base += 64) {
        int idx = base + lane;
        float w = 0.f; int s = 0;
        if (idx < end) {
            s = csr[idx].x;
            float e = as2[s] + ad;
            e = (e >= 0.f) ? e : NEG_SLOPE * e;
            w = expf(e);
        }
        den += w;
        int m = end - base; if (m > 64) m = 64;
        int jj = 0;
        for (; jj + 8 <= m; jj += 8) {
            float w0 = __shfl(w, jj + q, 64);
            int   s0 = __shfl(s, jj + q, 64);
            float w1_ = __shfl(w, jj + 4 + q, 64);
            int   s1 = __shfl(s, jj + 4 + q, 64);
            float h0 = h2[(size_t)s0 * 16 + c];
            float h1_ = h2[(size_t)s1 * 16 + c];
            acc += w0 * h0 + w1_ * h1_;
        }
        for (; jj < m; jj += 4) {
            float wj = __shfl(w, jj + q, 64);
            int sj = __shfl(s, jj + q, 64);
            acc += wj * h2[(size_t)sj * 16 + c];
        }
    }
#pragma unroll
    for (int off = 32; off >= 1; off >>= 1) den += __shfl_xor(den, off, 64);
    acc += __shfl_xor(acc, 16, 64);
    acc += __shfl_xor(acc, 32, 64);
    float v = acc / (den + GAT_EPS) + b2[c];
    float mmax = v;
#pragma unroll
    for (int off = 8; off >= 1; off >>= 1) mmax = fmaxf(mmax, __shfl_xor(mmax, off, 16));
    float ex = expf(v - mmax);
    float sum = ex;
#pragma unroll
    for (int off = 8; off >= 1; off >>= 1) sum += __shfl_xor(sum, off, 16);
    if (lane < 16) out[(size_t)d * 16 + c] = ex / sum;
}

// ---------------- launch ----------------

extern "C" void kernel_launch(void* const* d_in, const int* in_sizes, int n_in,
                              void* d_out, int out_size, void* d_ws, size_t ws_size,
                              hipStream_t stream) {
    const float* x        = (const float*)d_in[0];
    const float* W1       = (const float*)d_in[1];
    const float* att_src1 = (const float*)d_in[2];
    const float* att_dst1 = (const float*)d_in[3];
    const float* b1       = (const float*)d_in[4];
    const float* W2       = (const float*)d_in[5];
    const float* att_src2 = (const float*)d_in[6];
    const float* att_dst2 = (const float*)d_in[7];
    const float* b2       = (const float*)d_in[8];
    const int*   ei       = (const int*)d_in[9];   // [2, E]: src row then dst row

    char* p = (char*)d_ws;
    auto alloc = [&](size_t bytes) {
        char* r = p;
        p += (bytes + 255) & ~(size_t)255;
        return r;
    };
    _Float16* h1p  = (_Float16*)alloc(sizeof(_Float16) * (size_t)N_NODES * 128);
    float* w2tp    = (float*)alloc(sizeof(float) * 16 * 132);
    float* b1p     = (float*)alloc(sizeof(float) * 128);
    float* h2      = (float*)alloc(sizeof(float) * (size_t)N_NODES * 16);
    float* a_src   = (float*)alloc(sizeof(float) * N_NODES * 2);
    float* a_dst   = (float*)alloc(sizeof(float) * N_NODES * 2);
    float* as2     = (float*)alloc(sizeof(float) * N_NODES);
    float* ad2     = (float*)alloc(sizeof(float) * N_NODES);
    int* coarse    = (int*)alloc(sizeof(int) * NBKT * NCHUNK);
    int* cbase     = (int*)alloc(sizeof(int) * NBKT * NCHUNK);
    int* bb        = (int*)alloc(sizeof(int) * (NBKT + 1));
    int* row_start = (int*)alloc(sizeof(int) * (N_NODES + 1));
    int2* part     = (int2*)alloc(sizeof(int2) * (size_t)N_EDGES);
    int4* csr      = (int4*)alloc(sizeof(int4) * (size_t)N_EDGES);

    k_gh<<<GEMM_BLOCKS + NCHUNK + 1, 256, 0, stream>>>(x, W1, W2, b1, att_src1, att_dst1,
                                                       h1p, a_src, a_dst, ei, coarse, w2tp, b1p);
    k_cscan<<<1, 1024, 0, stream>>>(coarse, cbase, bb, row_start);
    k_partition<<<NCHUNK, 256, 0, stream>>>(ei, cbase, part);
    k_local<<<NBKT, 256, 0, stream>>>(part, bb, a_src, a_dst, row_start, csr);
    k_agg1f<<<N_NODES / 4, 256, 0, stream>>>(row_start, csr, h1p, b1p, w2tp, att_src2, att_dst2, h2, as2, ad2);
    k_agg2<<<N_NODES / 4, 256, 0, stream>>>(row_start, csr, h2, as2, ad2, b2, (float*)d_out);
}

// Round 16
// 265.824 us; speedup vs baseline: 1.0608x; 1.0608x over previous
//
#include <hip/hip_runtime.h>
#include <hip/hip_fp16.h>
#include <cstdint>
#include <cstddef>

#define N_NODES 50000
#define N_EDGES 1600000
#define NEG_SLOPE 0.2f
#define GAT_EPS 1e-16f

#define NCHUNK 128
#define CE (N_EDGES / NCHUNK)   // 12500
#define NBKT 196                 // ceil(50000/256)
#define GEMM_BLOCKS 782          // ceil(50000/64)

typedef _Float16 half8v __attribute__((ext_vector_type(8)));
typedef _Float16 half4v __attribute__((ext_vector_type(4)));
typedef float f32x4 __attribute__((ext_vector_type(4)));

// Channel permutation for h1 storage (MFMA C-reg native order):
// real c = ct*16 + m  <->  cperm = m*8 + ct

// ---------------- fused: MFMA GEMM blocks + histogram blocks + W2-prep block ----------------

__global__ __launch_bounds__(256) void k_gh(
    const float* __restrict__ x, const float* __restrict__ W1,
    const float* __restrict__ W2, const float* __restrict__ b1,
    const float* __restrict__ att_src, const float* __restrict__ att_dst,
    _Float16* __restrict__ h1p, float* __restrict__ a_src, float* __restrict__ a_dst,
    const int* __restrict__ ei, int* __restrict__ coarse,
    float* __restrict__ w2tp, float* __restrict__ b1p) {
    __shared__ __align__(16) char smem[34816];
    int t = threadIdx.x;
    int b = blockIdx.x;
    if (b == GEMM_BLOCKS + NCHUNK) {
        for (int i = t; i < 2112; i += 256) {   // 16 x 132
            int j = i / 132, kp = i % 132;
            float v = 0.f;
            if (kp < 128) {
                int real = (kp & 7) * 16 + (kp >> 3);
                v = W2[real * 16 + j];
            }
            w2tp[i] = v;
        }
        if (t < 128) {
            int real = (t & 7) * 16 + (t >> 3);
            b1p[t] = b1[real];
        }
        return;
    }
    if (b >= GEMM_BLOCKS) {
        int* h = (int*)smem;
        int g = b - GEMM_BLOCKS;
        if (t < NBKT) h[t] = 0;
        __syncthreads();
        int e0 = g * CE;
        for (int e = e0 + t; e < e0 + CE; e += 256)
            atomicAdd(&h[ei[N_EDGES + e] >> 8], 1);
        __syncthreads();
        if (t < NBKT) coarse[t * NCHUNK + g] = h[t];
        return;
    }
    _Float16* wl = (_Float16*)smem;      // [128][136]
    for (int j = t; j < 16384; j += 256) {
        int k = j >> 7, c = j & 127;
        wl[c * 136 + k] = (_Float16)W1[j];
    }
    __syncthreads();
    int wv = t >> 6, lane = t & 63;
    int m = lane & 15, q = lane >> 4;
    int nb = b * 64 + wv * 16;
    int grow = nb + m;
    const float* xrow = x + (size_t)((grow < N_NODES) ? grow : (N_NODES - 1)) * 128;
    f32x4 acc[8];
#pragma unroll
    for (int ct = 0; ct < 8; ++ct) acc[ct] = (f32x4){0.f, 0.f, 0.f, 0.f};
#pragma unroll
    for (int kc = 0; kc < 4; ++kc) {
        float4 u0 = *(const float4*)(xrow + kc * 32 + q * 8);
        float4 u1 = *(const float4*)(xrow + kc * 32 + q * 8 + 4);
        half8v a;
        a[0] = (_Float16)u0.x; a[1] = (_Float16)u0.y;
        a[2] = (_Float16)u0.z; a[3] = (_Float16)u0.w;
        a[4] = (_Float16)u1.x; a[5] = (_Float16)u1.y;
        a[6] = (_Float16)u1.z; a[7] = (_Float16)u1.w;
#pragma unroll
        for (int ct = 0; ct < 8; ++ct) {
            half8v bf = *(const half8v*)(wl + (ct * 16 + m) * 136 + kc * 32 + q * 8);
            acc[ct] = __builtin_amdgcn_mfma_f32_16x16x32_f16(a, bf, acc[ct], 0, 0, 0);
        }
    }
    float att_s[8], att_d[8];
#pragma unroll
    for (int ct = 0; ct < 8; ++ct) {
        att_s[ct] = att_src[ct * 16 + m];
        att_d[ct] = att_dst[ct * 16 + m];
    }
#pragma unroll
    for (int r = 0; r < 4; ++r) {
        int gn = nb + q * 4 + r;
        half8v hv;
        float ps0 = 0.f, ps1 = 0.f, pd0 = 0.f, pd1 = 0.f;
#pragma unroll
        for (int ct = 0; ct < 8; ++ct) {
            float v = acc[ct][r];
            hv[ct] = (_Float16)v;
            if (ct < 4) { ps0 += v * att_s[ct]; pd0 += v * att_d[ct]; }
            else        { ps1 += v * att_s[ct]; pd1 += v * att_d[ct]; }
        }
#pragma unroll
        for (int off = 8; off >= 1; off >>= 1) {
            ps0 += __shfl_xor(ps0, off, 64);
            ps1 += __shfl_xor(ps1, off, 64);
            pd0 += __shfl_xor(pd0, off, 64);
            pd1 += __shfl_xor(pd1, off, 64);
        }
        if (gn < N_NODES) {
            *(half8v*)(h1p + (size_t)gn * 128 + m * 8) = hv;
            if (m == 0) {
                a_src[gn * 2 + 0] = ps0;
                a_src[gn * 2 + 1] = ps1;
                a_dst[gn * 2 + 0] = pd0;
                a_dst[gn * 2 + 1] = pd1;
            }
        }
    }
}

// ---------------- CSR build (LDS atomics only) ----------------

__global__ __launch_bounds__(1024) void k_cscan(const int* __restrict__ coarse,
                                                int* __restrict__ cbase,
                                                int* __restrict__ bb,
                                                int* __restrict__ row_start) {
    __shared__ int cl[NBKT * NCHUNK];   // 100 KB
    __shared__ int btot[NBKT];
    __shared__ int bbase[NBKT];
    int t = threadIdx.x;
    for (int i = t; i < NBKT * NCHUNK; i += 1024) cl[i] = coarse[i];
    __syncthreads();
    if (t < NBKT) {
        int s = 0;
        for (int g = 0; g < NCHUNK; ++g) s += cl[t * NCHUNK + g];
        btot[t] = s;
    }
    __syncthreads();
    if (t == 0) {
        int base = 0;
        for (int b = 0; b < NBKT; ++b) { bbase[b] = base; base += btot[b]; }
    }
    __syncthreads();
    if (t < NBKT) {
        int run = bbase[t];
        bb[t] = run;
        for (int g = 0; g < NCHUNK; ++g) {
            cbase[t * NCHUNK + g] = run;
            run += cl[t * NCHUNK + g];
        }
    }
    if (t == 0) { bb[NBKT] = N_EDGES; row_start[N_NODES] = N_EDGES; }
}

__global__ __launch_bounds__(256) void k_partition(const int* __restrict__ ei,
                                                   const int* __restrict__ cbase,
                                                   int2* __restrict__ part) {
    __shared__ int loc[NBKT];
    int t = threadIdx.x, g = blockIdx.x;
    if (t < NBKT) loc[t] = cbase[t * NCHUNK + g];
    __syncthreads();
    int e0 = g * CE;
    for (int e = e0 + t; e < e0 + CE; e += 256) {
        int s = ei[e], d = ei[N_EDGES + e];
        int slot = atomicAdd(&loc[d >> 8], 1);
        part[slot] = make_int2(s, d);
    }
}

__global__ __launch_bounds__(256) void k_local(const int2* __restrict__ part,
                                               const int* __restrict__ bb,
                                               const float* __restrict__ a_src1,
                                               const float* __restrict__ a_dst1,
                                               int* __restrict__ row_start,
                                               int4* __restrict__ csr) {
    __shared__ int hist[256];
    __shared__ int fillv[256];
    __shared__ float2 adl[256];
    __shared__ int wtot[4];
    int t = threadIdx.x, b = blockIdx.x;
    int n0 = b << 8;
    int es = bb[b], ee = bb[b + 1];
    hist[t] = 0;
    if (n0 + t < N_NODES) adl[t] = ((const float2*)a_dst1)[n0 + t];
    __syncthreads();
    for (int e = es + t; e < ee; e += 256) atomicAdd(&hist[part[e].y - n0], 1);
    __syncthreads();
    int lane = t & 63, w = t >> 6;
    int v = hist[t], x = v;
#pragma unroll
    for (int off = 1; off < 64; off <<= 1) {
        int y = __shfl_up(x, off, 64);
        if (lane >= off) x += y;
    }
    if (lane == 63) wtot[w] = x;
    __syncthreads();
    int woff = 0;
    for (int i = 0; i < w; ++i) woff += wtot[i];
    int excl = woff + x - v;
    if (n0 + t < N_NODES) row_start[n0 + t] = es + excl;
    fillv[t] = excl;
    __syncthreads();
    for (int e = es + t; e < ee; e += 256) {
        int2 sd = part[e];
        int j = sd.y - n0;
        int slot = es + atomicAdd(&fillv[j], 1);
        float2 as = ((const float2*)a_src1)[sd.x];
        float2 ad = adl[j];
        float e0 = as.x + ad.x; e0 = (e0 >= 0.f) ? e0 : NEG_SLOPE * e0;
        float e1 = as.y + ad.y; e1 = (e1 >= 0.f) ? e1 : NEG_SLOPE * e1;
        csr[slot] = make_int4(sd.x, __float_as_int(expf(e0)), __float_as_int(expf(e1)), 0);
    }
}

// ---------------- Layer 1 aggregation + ELU + fused layer-2 GEMM ----------------
// One wave per node, pair-scheme halves; channels in PERMUTED space.
// 8 edges/iter (4 per half — R12 structure, 71% occupancy) + fma_mix accumulate.

__global__ __launch_bounds__(256) void k_agg1f(
    const int* __restrict__ row_start, const int4* __restrict__ csr,
    const _Float16* __restrict__ h1p, const float* __restrict__ b1p,
    const float* __restrict__ w2tp,
    const float* __restrict__ att_src2, const float* __restrict__ att_dst2,
    float* __restrict__ h2, float* __restrict__ as2, float* __restrict__ ad2) {
    __shared__ float w2l[16 * 132];
    __shared__ float rows[4][128];
    int t = threadIdx.x;
    for (int i = t; i < 528; i += 256) ((float4*)w2l)[i] = ((const float4*)w2tp)[i];
    __syncthreads();
    int wv = t >> 6, lane = t & 63;
    int d = blockIdx.x * 4 + wv;
    int row = row_start[d], end = row_start[d + 1];
    int half = lane >> 5;
    int L = lane & 31;
    int c0 = L * 4;
    int head = L & 1;
    float den = 0.f;
    float4 acc = make_float4(0.f, 0.f, 0.f, 0.f);
    int i = row;
    for (; i + 8 <= end; i += 8) {
#pragma unroll
        for (int p = 0; p < 4; ++p) {
            int idx = i + 2 * p + half;
            int4 e4 = csr[idx];
            float we = head ? __int_as_float(e4.z) : __int_as_float(e4.y);
            half4v hv = *(const half4v*)(h1p + (size_t)e4.x * 128 + c0);
            den += we;
            acc.x += we * (float)hv[0];
            acc.y += we * (float)hv[1];
            acc.z += we * (float)hv[2];
            acc.w += we * (float)hv[3];
        }
    }
    for (; i < end; i += 2) {
        int idx = i + half;
        bool ok = idx < end;
        int idxc = ok ? idx : i;
        int4 e4 = csr[idxc];
        float we = head ? __int_as_float(e4.z) : __int_as_float(e4.y);
        if (!ok) we = 0.f;
        half4v hv = *(const half4v*)(h1p + (size_t)e4.x * 128 + c0);
        den += we;
        acc.x += we * (float)hv[0];
        acc.y += we * (float)hv[1];
        acc.z += we * (float)hv[2];
        acc.w += we * (float)hv[3];
    }
    den += __shfl_xor(den, 32, 64);
    acc.x += __shfl_xor(acc.x, 32, 64);
    acc.y += __shfl_xor(acc.y, 32, 64);
    acc.z += __shfl_xor(acc.z, 32, 64);
    acc.w += __shfl_xor(acc.w, 32, 64);
    float inv = 1.f / (den + GAT_EPS);
    float4 bv = ((const float4*)b1p)[L];
    float o0 = acc.x * inv + bv.x;
    float o1 = acc.y * inv + bv.y;
    float o2 = acc.z * inv + bv.z;
    float o3 = acc.w * inv + bv.w;
    o0 = (o0 > 0.f) ? o0 : expm1f(o0);
    o1 = (o1 > 0.f) ? o1 : expm1f(o1);
    o2 = (o2 > 0.f) ? o2 : expm1f(o2);
    o3 = (o3 > 0.f) ? o3 : expm1f(o3);
    if (half == 0) *(float4*)(&rows[wv][c0]) = make_float4(o0, o1, o2, o3);
    // fused gemm2, q-rotated phases
    int j = lane & 15, q = lane >> 4;
    const float* r = rows[wv];
    const float* wt = &w2l[j * 132];
    int k0 = q * 32;
    float acc2 = 0.f;
#pragma unroll
    for (int sI = 0; sI < 8; ++sI) {
        int sp = ((sI + q) & 7) * 4;
        float4 rv = *(const float4*)(r + k0 + sp);
        float4 w4 = *(const float4*)(wt + k0 + sp);
        acc2 += rv.x * w4.x + rv.y * w4.y + rv.z * w4.z + rv.w * w4.w;
    }
    acc2 += __shfl_xor(acc2, 16, 64);
    acc2 += __shfl_xor(acc2, 32, 64);
    if (lane < 16) {
        h2[(size_t)d * 16 + j] = acc2;
        float ps = acc2 * att_src2[j];
        float pd = acc2 * att_dst2[j];
#pragma unroll
        for (int off = 8; off >= 1; off >>= 1) {
            ps += __shfl_xor(ps, off, 64);
            pd += __shfl_xor(pd, off, 64);
        }
        if (lane == 0) { as2[d] = ps; ad2[d] = pd; }
    }
}

// ---------------- Layer 2 aggregation + bias + softmax: one wave per node ----------------

__global__ __launch_bounds__(256) void k_agg2(
    const int* __restrict__ row_start, const int4* __restrict__ csr,
    const float* __restrict__ h2, const float* __restrict__ as2,
    const float* __restrict__ ad2, const float* __restrict__ b2,
    float* __restrict__ out) {
    int t = threadIdx.x;
    int wv = t >> 6, lane = t & 63;
    int d = blockIdx.x * 4 + wv;
    int row = row_start[d], end = row_start[d + 1];
    float ad = ad2[d];
    int c = lane & 15, q = lane >> 4;
    float den = 0.f, acc = 0.f;
    for (int base = row; base < end; base += 64) {
        int idx = base + lane;
        float w = 0.f; int s = 0;
        if (idx < end) {
            s = csr[idx].x;
            float e = as2[s] + ad;
            e = (e >= 0.f) ? e : NEG_SLOPE * e;
            w = expf(e);
        }
        den += w;
        int m = end - base; if (m > 64) m = 64;
        int jj = 0;
        for (; jj + 8 <= m; jj += 8) {
            float w0 = __shfl(w, jj + q, 64);
            int   s0 = __shfl(s, jj + q, 64);
            float w1_ = __shfl(w, jj + 4 + q, 64);
            int   s1 = __shfl(s, jj + 4 + q, 64);
            float h0 = h2[(size_t)s0 * 16 + c];
            float h1_ = h2[(size_t)s1 * 16 + c];
            acc += w0 * h0 + w1_ * h1_;
        }
        for (; jj < m; jj += 4) {
            float wj = __shfl(w, jj + q, 64);
            int sj = __shfl(s, jj + q, 64);
            acc += wj * h2[(size_t)sj * 16 + c];
        }
    }
#pragma unroll
    for (int off = 32; off >= 1; off >>= 1) den += __shfl_xor(den, off, 64);
    acc += __shfl_xor(acc, 16, 64);
    acc += __shfl_xor(acc, 32, 64);
    float v = acc / (den + GAT_EPS) + b2[c];
    float mmax = v;
#pragma unroll
    for (int off = 8; off >= 1; off >>= 1) mmax = fmaxf(mmax, __shfl_xor(mmax, off, 16));
    float ex = expf(v - mmax);
    float sum = ex;
#pragma unroll
    for (int off = 8; off >= 1; off >>= 1) sum += __shfl_xor(sum, off, 16);
    if (lane < 16) out[(size_t)d * 16 + c] = ex / sum;
}

// ---------------- launch ----------------

extern "C" void kernel_launch(void* const* d_in, const int* in_sizes, int n_in,
                              void* d_out, int out_size, void* d_ws, size_t ws_size,
                              hipStream_t stream) {
    const float* x        = (const float*)d_in[0];
    const float* W1       = (const float*)d_in[1];
    const float* att_src1 = (const float*)d_in[2];
    const float* att_dst1 = (const float*)d_in[3];
    const float* b1       = (const float*)d_in[4];
    const float* W2       = (const float*)d_in[5];
    const float* att_src2 = (const float*)d_in[6];
    const float* att_dst2 = (const float*)d_in[7];
    const float* b2       = (const float*)d_in[8];
    const int*   ei       = (const int*)d_in[9];   // [2, E]: src row then dst row

    char* p = (char*)d_ws;
    auto alloc = [&](size_t bytes) {
        char* r = p;
        p += (bytes + 255) & ~(size_t)255;
        return r;
    };
    _Float16* h1p  = (_Float16*)alloc(sizeof(_Float16) * (size_t)N_NODES * 128);
    float* w2tp    = (float*)alloc(sizeof(float) * 16 * 132);
    float* b1p     = (float*)alloc(sizeof(float) * 128);
    float* h2      = (float*)alloc(sizeof(float) * (size_t)N_NODES * 16);
    float* a_src   = (float*)alloc(sizeof(float) * N_NODES * 2);
    float* a_dst   = (float*)alloc(sizeof(float) * N_NODES * 2);
    float* as2     = (float*)alloc(sizeof(float) * N_NODES);
    float* ad2     = (float*)alloc(sizeof(float) * N_NODES);
    int* coarse    = (int*)alloc(sizeof(int) * NBKT * NCHUNK);
    int* cbase     = (int*)alloc(sizeof(int) * NBKT * NCHUNK);
    int* bb        = (int*)alloc(sizeof(int) * (NBKT + 1));
    int* row_start = (int*)alloc(sizeof(int) * (N_NODES + 1));
    int2* part     = (int2*)alloc(sizeof(int2) * (size_t)N_EDGES);
    int4* csr      = (int4*)alloc(sizeof(int4) * (size_t)N_EDGES);

    k_gh<<<GEMM_BLOCKS + NCHUNK + 1, 256, 0, stream>>>(x, W1, W2, b1, att_src1, att_dst1,
                                                       h1p, a_src, a_dst, ei, coarse, w2tp, b1p);
    k_cscan<<<1, 1024, 0, stream>>>(coarse, cbase, bb, row_start);
    k_partition<<<NCHUNK, 256, 0, stream>>>(ei, cbase, part);
    k_local<<<NBKT, 256, 0, stream>>>(part, bb, a_src, a_dst, row_start, csr);
    k_agg1f<<<N_NODES / 4, 256, 0, stream>>>(row_start, csr, h1p, b1p, w2tp, att_src2, att_dst2, h2, as2, ad2);
    k_agg2<<<N_NODES / 4, 256, 0, stream>>>(row_start, csr, h2, as2, ad2, b2, (float*)d_out);
}